// Round 4
// baseline (55.842 us; speedup 1.0000x reference)
//
#include <hip/hip_runtime.h>
#include <hip/hip_bf16.h>
#include <math.h>

// Problem dims (fixed by reference setup_inputs)
#define B 8
#define NPTS 20000
#define M 1024
#define H 1024
#define BN_EPS 1e-5f

// BPS: 125 chunks * 160 points = 20000; 4 waves/block each own a 40-pt quarter
#define BPS_CHUNK 160
#define BPS_NCHUNK 125
#define KM 16                     // basis points per thread (lane-major m)

// layer1: 64 blocks = 4 i-tiles x 16 m-chunks of 64
#define L1_MCHUNK 64
#define L1_NMCHUNK (M / L1_MCHUNK)   // 16

typedef float f2 __attribute__((ext_vector_type(2)));

// ---------------------------------------------------------------------------
// Kernel 1: BPS partial min. grid=(125,8), block=256 (4 waves).
// Wave w handles points [w*40, w*40+40) x ALL m (16 m per lane, lane-major).
// Inner: t = min_n(|p|^2 - 2 p.b) with packed-fp32 fma over point pairs.
// Block combines 4 wave-partials in LDS, adds |b|^2, clamps, writes
// pmin[chunk][b][m] (no atomics).
// ---------------------------------------------------------------------------
__global__ __launch_bounds__(256) void bps_kernel(const float* __restrict__ x,
                                                  const float* __restrict__ basis,
                                                  float* __restrict__ pmin) {
    __shared__ f2 sx[BPS_CHUNK / 2], sy[BPS_CHUNK / 2], sz[BPS_CHUNK / 2], sw[BPS_CHUNK / 2];
    __shared__ float smin[4][M];       // [wave][m] : 4*1024 floats = 16 KB
    const int chunk = blockIdx.x;
    const int b = blockIdx.y;
    const int tid = threadIdx.x;
    const int lane = tid & 63;
    const int w = tid >> 6;
    const int n0 = chunk * BPS_CHUNK;
    const float* xb = x + (size_t)b * 3 * NPTS;

    if (tid < BPS_CHUNK) {
        float px = xb[n0 + tid];
        float py = xb[NPTS + n0 + tid];
        float pz = xb[2 * NPTS + n0 + tid];
        ((float*)sx)[tid] = px;
        ((float*)sy)[tid] = py;
        ((float*)sz)[tid] = pz;
        ((float*)sw)[tid] = px * px + py * py + pz * pz;
    }

    // 16 basis points per thread: m = lane + 64*i
    float nbx[KM], nby[KM], nbz[KM], bb2[KM];
#pragma unroll
    for (int i = 0; i < KM; ++i) {
        int m = lane + 64 * i;
        float bx = basis[m * 3 + 0];
        float by = basis[m * 3 + 1];
        float bz = basis[m * 3 + 2];
        nbx[i] = -2.0f * bx;
        nby[i] = -2.0f * by;
        nbz[i] = -2.0f * bz;
        bb2[i] = bx * bx + by * by + bz * bz;
    }
    float acc[KM];
#pragma unroll
    for (int i = 0; i < KM; ++i) acc[i] = INFINITY;
    __syncthreads();

    const int j0 = w * (BPS_CHUNK / 8);     // 20 pairs per wave
#pragma unroll 2
    for (int j = j0; j < j0 + BPS_CHUNK / 8; ++j) {
        f2 X = sx[j];
        f2 Y = sy[j];
        f2 Z = sz[j];
        f2 W = sw[j];
#pragma unroll
        for (int i = 0; i < KM; ++i) {
            f2 s = __builtin_elementwise_fma(X, (f2){nbx[i], nbx[i]}, W);
            s = __builtin_elementwise_fma(Y, (f2){nby[i], nby[i]}, s);
            s = __builtin_elementwise_fma(Z, (f2){nbz[i], nbz[i]}, s);
            acc[i] = fminf(acc[i], fminf(s.x, s.y));
        }
    }

    // wave partial -> LDS (conflict-free: lane-major, stride 4B)
#pragma unroll
    for (int i = 0; i < KM; ++i) {
        smin[w][lane + 64 * i] = acc[i] + bb2[i];
    }
    __syncthreads();

    // combine 4 waves, clamp, write (4 m per thread, coalesced)
#pragma unroll
    for (int q = 0; q < 4; ++q) {
        int m = tid + q * 256;
        float v = fminf(fminf(smin[0][m], smin[1][m]), fminf(smin[2][m], smin[3][m]));
        pmin[((size_t)chunk * B + b) * M + m] = fmaxf(v, 0.0f);
    }
}

// ---------------------------------------------------------------------------
// Kernel 2: reduce 125 chunk-partials -> bn1 feature. grid=32, block=256.
// Thread t owns (b = t>>10, m = t&1023); loads are coalesced over m.
// ---------------------------------------------------------------------------
__global__ __launch_bounds__(256) void reduce_kernel(const float* __restrict__ pmin,
                                                     const float* __restrict__ g1,
                                                     const float* __restrict__ bb1,
                                                     const float* __restrict__ rm1,
                                                     const float* __restrict__ rv1,
                                                     float* __restrict__ fout) {
    const int t = blockIdx.x * 256 + threadIdx.x;   // 0..8191
    const int b = t >> 10;
    const int m = t & (M - 1);
    float v = INFINITY;
#pragma unroll 25
    for (int c = 0; c < BPS_NCHUNK; ++c) {
        v = fminf(v, pmin[((size_t)c * B + b) * M + m]);
    }
    float f = sqrtf(v);
    float sc = g1[m] * rsqrtf(rv1[m] + BN_EPS);
    fout[t] = (f - rm1[m]) * sc + bb1[m];
}

// ---------------------------------------------------------------------------
// Kernel 3: layer1 GEMV partials. grid=64 (4 i-tiles x 16 m-chunks), block=256.
// Thread owns output i, accumulates 8 batches over its 64-m chunk.
// ---------------------------------------------------------------------------
__global__ __launch_bounds__(256) void layer1_kernel(const float* __restrict__ fout,
                                                     const float* __restrict__ w1,
                                                     float* __restrict__ hpart) {
    __shared__ float fs[B][L1_MCHUNK];
    const int tid = threadIdx.x;
    const int it = blockIdx.x & 3;
    const int mc = blockIdx.x >> 2;
    const int i = it * 256 + tid;
    const int m0 = mc * L1_MCHUNK;

    // 512 LDS entries, 256 threads -> strided loop (2 iterations)
    for (int e = tid; e < B * L1_MCHUNK; e += 256) {
        int bb = e >> 6;                      // /64
        int ml = e & (L1_MCHUNK - 1);
        fs[bb][ml] = fout[bb * M + m0 + ml];
    }
    __syncthreads();

    float acc[B] = {0, 0, 0, 0, 0, 0, 0, 0};
    const float* wrow = w1 + (size_t)i * M + m0;
#pragma unroll
    for (int ml = 0; ml < L1_MCHUNK; ml += 4) {
        float4 wv = *reinterpret_cast<const float4*>(wrow + ml);
#pragma unroll
        for (int bb = 0; bb < B; ++bb) {
            float4 fv = *reinterpret_cast<const float4*>(&fs[bb][ml]);
            acc[bb] = fmaf(fv.x, wv.x, acc[bb]);
            acc[bb] = fmaf(fv.y, wv.y, acc[bb]);
            acc[bb] = fmaf(fv.z, wv.z, acc[bb]);
            acc[bb] = fmaf(fv.w, wv.w, acc[bb]);
        }
    }
#pragma unroll
    for (int bb = 0; bb < B; ++bb) hpart[((size_t)mc * B + bb) * H + i] = acc[bb];
}

// ---------------------------------------------------------------------------
// Kernel 4: sum partials + b1, relu, bn2, dot w2, + b2. grid=8 blocks.
// ---------------------------------------------------------------------------
__global__ __launch_bounds__(256) void final_kernel(const float* __restrict__ hpart,
                                                    const float* __restrict__ b1,
                                                    const float* __restrict__ g2,
                                                    const float* __restrict__ bb2v,
                                                    const float* __restrict__ rm2,
                                                    const float* __restrict__ rv2,
                                                    const float* __restrict__ w2,
                                                    const float* __restrict__ b2,
                                                    float* __restrict__ out) {
    const int b = blockIdx.x;
    const int tid = threadIdx.x;
    float sum = 0.0f;
    for (int i = tid; i < H; i += 256) {
        float hs = 0.0f;
#pragma unroll
        for (int mc = 0; mc < L1_NMCHUNK; ++mc) {
            hs += hpart[((size_t)mc * B + b) * H + i];
        }
        float v = fmaxf(hs + b1[i], 0.0f);
        float sc = g2[i] * rsqrtf(rv2[i] + BN_EPS);
        v = (v - rm2[i]) * sc + bb2v[i];
        sum += v * w2[i];
    }
#pragma unroll
    for (int off = 32; off > 0; off >>= 1) sum += __shfl_down(sum, off, 64);
    __shared__ float wsum[4];
    if ((tid & 63) == 0) wsum[tid >> 6] = sum;
    __syncthreads();
    if (tid == 0) out[b] = wsum[0] + wsum[1] + wsum[2] + wsum[3] + b2[0];
}

// ---------------------------------------------------------------------------
extern "C" void kernel_launch(void* const* d_in, const int* in_sizes, int n_in,
                              void* d_out, int out_size, void* d_ws, size_t ws_size,
                              hipStream_t stream) {
    const float* x      = (const float*)d_in[0];
    const float* basis  = (const float*)d_in[1];
    const float* bn1_g  = (const float*)d_in[2];
    const float* bn1_b  = (const float*)d_in[3];
    const float* bn1_rm = (const float*)d_in[4];
    const float* bn1_rv = (const float*)d_in[5];
    const float* w1     = (const float*)d_in[6];
    const float* b1     = (const float*)d_in[7];
    const float* bn2_g  = (const float*)d_in[8];
    const float* bn2_b  = (const float*)d_in[9];
    const float* bn2_rm = (const float*)d_in[10];
    const float* bn2_rv = (const float*)d_in[11];
    const float* w2     = (const float*)d_in[12];
    const float* b2     = (const float*)d_in[13];
    float* out = (float*)d_out;

    // workspace (all fully rewritten every call)
    char* ws = (char*)d_ws;
    float* pmin  = (float*)ws;                                      // 125*8*1024 f = 4.2MB
    float* fout  = (float*)(ws + (size_t)BPS_NCHUNK * B * M * 4);   // 8*1024 f
    float* hpart = (float*)(ws + (size_t)BPS_NCHUNK * B * M * 4 + B * M * 4); // 16*8*1024 f

    dim3 g1g(BPS_NCHUNK, B);
    bps_kernel<<<g1g, 256, 0, stream>>>(x, basis, pmin);

    reduce_kernel<<<B * M / 256, 256, 0, stream>>>(pmin, bn1_g, bn1_b, bn1_rm, bn1_rv, fout);

    layer1_kernel<<<4 * L1_NMCHUNK, 256, 0, stream>>>(fout, w1, hpart);

    final_kernel<<<B, 256, 0, stream>>>(hpart, b1, bn2_g, bn2_b, bn2_rm, bn2_rv, w2, b2, out);
}

// Round 5
// 49.428 us; speedup vs baseline: 1.1298x; 1.1298x over previous
//
#include <hip/hip_runtime.h>
#include <hip/hip_bf16.h>
#include <math.h>

// Problem dims (fixed by reference setup_inputs)
#define B 8
#define NPTS 20000
#define M 1024
#define H 1024
#define BN_EPS 1e-5f

// BPS: 125 chunks * 160 points = 20000; 4 waves/block each own a 20-pair slice
#define BPS_CHUNK 160
#define BPS_NCHUNK 125
#define KM 16                     // basis points per thread (lane-major m)

typedef float f2 __attribute__((ext_vector_type(2)));

// ---------------------------------------------------------------------------
// Kernel 1: BPS partial min. grid=(125,8), block=256 (4 waves).
// Wave w handles point-pairs [w*20, w*20+20) x ALL m (16 m per lane).
// t = min_n(|p|^2 - 2 p.b) via packed-fp32 fma; block LDS-combines the 4
// wave partials, adds |b|^2, clamps >=0, then one uint atomicMin per m into
// fmin[b][m]. fmin pre-initialized to 0x7F7F7F7F (= 3.4e38) via memset.
// atomicMin on non-negative float bits == float min; order-independent.
// ---------------------------------------------------------------------------
__global__ __launch_bounds__(256) void bps_kernel(const float* __restrict__ x,
                                                  const float* __restrict__ basis,
                                                  unsigned int* __restrict__ fmin) {
    __shared__ f2 sx[BPS_CHUNK / 2], sy[BPS_CHUNK / 2], sz[BPS_CHUNK / 2], sw[BPS_CHUNK / 2];
    __shared__ float smin[4][M];       // 16 KB
    const int chunk = blockIdx.x;
    const int b = blockIdx.y;
    const int tid = threadIdx.x;
    const int lane = tid & 63;
    const int w = tid >> 6;
    const int n0 = chunk * BPS_CHUNK;
    const float* xb = x + (size_t)b * 3 * NPTS;

    if (tid < BPS_CHUNK) {
        float px = xb[n0 + tid];
        float py = xb[NPTS + n0 + tid];
        float pz = xb[2 * NPTS + n0 + tid];
        ((float*)sx)[tid] = px;
        ((float*)sy)[tid] = py;
        ((float*)sz)[tid] = pz;
        ((float*)sw)[tid] = px * px + py * py + pz * pz;
    }

    // 16 basis points per thread: m = lane + 64*i
    float nbx[KM], nby[KM], nbz[KM], bb2[KM];
#pragma unroll
    for (int i = 0; i < KM; ++i) {
        int m = lane + 64 * i;
        float bx = basis[m * 3 + 0];
        float by = basis[m * 3 + 1];
        float bz = basis[m * 3 + 2];
        nbx[i] = -2.0f * bx;
        nby[i] = -2.0f * by;
        nbz[i] = -2.0f * bz;
        bb2[i] = bx * bx + by * by + bz * bz;
    }
    float acc[KM];
#pragma unroll
    for (int i = 0; i < KM; ++i) acc[i] = INFINITY;
    __syncthreads();

    const int j0 = w * (BPS_CHUNK / 8);     // 20 pairs per wave
#pragma unroll 2
    for (int j = j0; j < j0 + BPS_CHUNK / 8; ++j) {
        f2 X = sx[j];
        f2 Y = sy[j];
        f2 Z = sz[j];
        f2 W = sw[j];
#pragma unroll
        for (int i = 0; i < KM; ++i) {
            f2 s = __builtin_elementwise_fma(X, (f2){nbx[i], nbx[i]}, W);
            s = __builtin_elementwise_fma(Y, (f2){nby[i], nby[i]}, s);
            s = __builtin_elementwise_fma(Z, (f2){nbz[i], nbz[i]}, s);
            acc[i] = fminf(acc[i], fminf(s.x, s.y));
        }
    }

    // wave partial -> LDS (lane-major, conflict-free)
#pragma unroll
    for (int i = 0; i < KM; ++i) {
        smin[w][lane + 64 * i] = acc[i] + bb2[i];
    }
    __syncthreads();

    // combine 4 waves, clamp, one atomic per m
#pragma unroll
    for (int q = 0; q < 4; ++q) {
        int m = tid + q * 256;
        float v = fminf(fminf(smin[0][m], smin[1][m]), fminf(smin[2][m], smin[3][m]));
        v = fmaxf(v, 0.0f);                 // clip(min,0) == min(clip)
        atomicMin(&fmin[b * M + m], __float_as_uint(v));
    }
}

// ---------------------------------------------------------------------------
// Kernel 2: fused bn1 + layer1 + relu + bn2 + w2-scale.
// grid=256 blocks, block=256 (4 waves). Block stages bn1 features fs[8][1024]
// in LDS (32 KB); wave r computes the FULL M-dot for row i = bid*4 + r for
// all 8 batches, shuffle-reduces, lane0 applies b1/relu/bn2 and writes
// psum[i][b] = w2[i] * bn2(relu(h[b][i])).
// ---------------------------------------------------------------------------
__global__ __launch_bounds__(256) void mlp_kernel(const unsigned int* __restrict__ fmin,
                                                  const float* __restrict__ g1,
                                                  const float* __restrict__ bb1,
                                                  const float* __restrict__ rm1,
                                                  const float* __restrict__ rv1,
                                                  const float* __restrict__ w1,
                                                  const float* __restrict__ b1,
                                                  const float* __restrict__ g2,
                                                  const float* __restrict__ bb2v,
                                                  const float* __restrict__ rm2,
                                                  const float* __restrict__ rv2,
                                                  const float* __restrict__ w2,
                                                  float* __restrict__ psum) {
    __shared__ float fs[B * M];             // 32 KB
    const int tid = threadIdx.x;

    for (int e = tid; e < B * M; e += 256) {
        int m = e & (M - 1);
        float f = sqrtf(__uint_as_float(fmin[e]));
        float sc = g1[m] * rsqrtf(rv1[m] + BN_EPS);
        fs[e] = (f - rm1[m]) * sc + bb1[m];
    }
    __syncthreads();

    const int lane = tid & 63;
    const int wv = tid >> 6;
    const int i = blockIdx.x * 4 + wv;      // output row, 0..1023
    const float* wrow = w1 + (size_t)i * M;

    float hsum[B] = {0, 0, 0, 0, 0, 0, 0, 0};
#pragma unroll
    for (int seg = 0; seg < 4; ++seg) {
        int m0 = seg * 256 + lane * 4;
        float4 wv4 = *reinterpret_cast<const float4*>(wrow + m0);
#pragma unroll
        for (int bb = 0; bb < B; ++bb) {
            float4 fv = *reinterpret_cast<const float4*>(&fs[bb * M + m0]);
            hsum[bb] = fmaf(fv.x, wv4.x, hsum[bb]);
            hsum[bb] = fmaf(fv.y, wv4.y, hsum[bb]);
            hsum[bb] = fmaf(fv.z, wv4.z, hsum[bb]);
            hsum[bb] = fmaf(fv.w, wv4.w, hsum[bb]);
        }
    }
#pragma unroll
    for (int bb = 0; bb < B; ++bb) {
#pragma unroll
        for (int off = 32; off > 0; off >>= 1) {
            hsum[bb] += __shfl_down(hsum[bb], off, 64);
        }
    }
    if (lane == 0) {
        float b1i = b1[i];
        float sc2 = g2[i] * rsqrtf(rv2[i] + BN_EPS);
        float rm = rm2[i];
        float bt = bb2v[i];
        float w2i = w2[i];
#pragma unroll
        for (int bb = 0; bb < B; ++bb) {
            float v = fmaxf(hsum[bb] + b1i, 0.0f);
            v = (v - rm) * sc2 + bt;
            psum[(size_t)i * B + bb] = v * w2i;
        }
    }
}

// ---------------------------------------------------------------------------
// Kernel 3: out[b] = b2 + sum_i psum[i][b]. One block, 256 threads:
// thread t owns (b = t>>5, i-slice = t&31); 32 partials per b reduced via
// width-32 shuffles (b is constant within each 32-lane half-wave).
// ---------------------------------------------------------------------------
__global__ __launch_bounds__(256) void out_kernel(const float* __restrict__ psum,
                                                  const float* __restrict__ b2,
                                                  float* __restrict__ out) {
    const int tid = threadIdx.x;
    const int bb = tid >> 5;
    const int sl = tid & 31;
    float s = 0.0f;
    for (int i = sl; i < H; i += 32) {
        s += psum[(size_t)i * B + bb];
    }
#pragma unroll
    for (int off = 16; off > 0; off >>= 1) {
        s += __shfl_down(s, off, 32);
    }
    if (sl == 0) {
        out[bb] = s + b2[0];
    }
}

// ---------------------------------------------------------------------------
extern "C" void kernel_launch(void* const* d_in, const int* in_sizes, int n_in,
                              void* d_out, int out_size, void* d_ws, size_t ws_size,
                              hipStream_t stream) {
    const float* x      = (const float*)d_in[0];
    const float* basis  = (const float*)d_in[1];
    const float* bn1_g  = (const float*)d_in[2];
    const float* bn1_b  = (const float*)d_in[3];
    const float* bn1_rm = (const float*)d_in[4];
    const float* bn1_rv = (const float*)d_in[5];
    const float* w1     = (const float*)d_in[6];
    const float* b1     = (const float*)d_in[7];
    const float* bn2_g  = (const float*)d_in[8];
    const float* bn2_b  = (const float*)d_in[9];
    const float* bn2_rm = (const float*)d_in[10];
    const float* bn2_rv = (const float*)d_in[11];
    const float* w2     = (const float*)d_in[12];
    const float* b2     = (const float*)d_in[13];
    float* out = (float*)d_out;

    // workspace: fmin u32[8192] (32 KB) | psum f32[8192] (32 KB)
    unsigned int* fmin = (unsigned int*)d_ws;
    float* psum = (float*)((char*)d_ws + (size_t)B * M * 4);

    // init fmin to 0x7F7F7F7F (= 3.39e38, acts as +inf for dist^2 <= ~100)
    hipMemsetAsync(fmin, 0x7F, (size_t)B * M * 4, stream);

    dim3 g1g(BPS_NCHUNK, B);
    bps_kernel<<<g1g, 256, 0, stream>>>(x, basis, fmin);

    mlp_kernel<<<H / 4, 256, 0, stream>>>(fmin, bn1_g, bn1_b, bn1_rm, bn1_rv, w1, b1,
                                          bn2_g, bn2_b, bn2_rm, bn2_rv, w2, psum);

    out_kernel<<<1, 256, 0, stream>>>(psum, b2, out);
}